// Round 7
// baseline (200.611 us; speedup 1.0000x reference)
//
#include <hip/hip_runtime.h>
#include <stdint.h>

#define HIDDEN 1024
#define MROWS  32768
#define NPROTO 9
#define ZOFF   (MROWS * NPROTO)   // 294912 floats of logits, then z

typedef __bf16 bf16x8 __attribute__((ext_vector_type(8)));
typedef float  f32x4  __attribute__((ext_vector_type(4)));

__device__ __forceinline__ unsigned short f2bf(float f) {
    unsigned u = __float_as_uint(f);
    u += 0x7fffu + ((u >> 16) & 1u);   // round-to-nearest-even
    return (unsigned short)(u >> 16);
}
__device__ __forceinline__ float bf2f(unsigned short u) {
    return __uint_as_float(((unsigned)u) << 16);
}

// ---------------- prep: W*mask -> bf16 ----------------
__global__ void k_conv_w(const float* __restrict__ w, const float* __restrict__ m,
                         unsigned short* __restrict__ dst, int n8) {
    int i0 = blockIdx.x * blockDim.x + threadIdx.x;
    int stride = gridDim.x * blockDim.x;
    for (int i = i0; i < n8; i += stride) {
        const float4* pw = (const float4*)(w + (size_t)i * 8);
        const float4* pm = (const float4*)(m + (size_t)i * 8);
        float4 a = pw[0], b = pw[1], c = pm[0], d = pm[1];
        union { unsigned short us[8]; uint4 v; } o;
        o.us[0] = f2bf(a.x * c.x); o.us[1] = f2bf(a.y * c.y);
        o.us[2] = f2bf(a.z * c.z); o.us[3] = f2bf(a.w * c.w);
        o.us[4] = f2bf(b.x * d.x); o.us[5] = f2bf(b.y * d.y);
        o.us[6] = f2bf(b.z * d.z); o.us[7] = f2bf(b.w * d.w);
        *(uint4*)(dst + (size_t)i * 8) = o.v;
    }
}

// ---------------- prep: l2-normalized prototypes (first 9 rows) ----------------
__global__ void k_proto(const float* __restrict__ proto, float* __restrict__ pn) {
    __shared__ float red[4];
    int t = threadIdx.x, k = blockIdx.x;
    float4 v = *(const float4*)(proto + (size_t)k * HIDDEN + t * 4);
    float ss = v.x * v.x + v.y * v.y + v.z * v.z + v.w * v.w;
    #pragma unroll
    for (int m = 1; m < 64; m <<= 1) ss += __shfl_xor(ss, m);
    if ((t & 63) == 0) red[t >> 6] = ss;
    __syncthreads();
    ss = red[0] + red[1] + red[2] + red[3];
    float inv = 1.0f / fmaxf(sqrtf(ss), 1e-12f);
    float4 o; o.x = v.x * inv; o.y = v.y * inv; o.z = v.z * inv; o.w = v.w * inv;
    *(float4*)(pn + (size_t)k * HIDDEN + t * 4) = o;
}

// ---------------- main GEMM: zp[m][o] = bf16( sum_d h[m][d] * wm[o][d] ) ----------------
// 128x128/BK=32, 4 waves, XCD swizzle (verified R5/R6).
// A: read f32 h -> reg -> cvt bf16 -> ds_write to PADDED LDS rows (40 shorts = 80B):
//    write ~2-way banks, fragment reads conflict-free (fixes R5's 16-way write conflict).
// B: global_load_lds with SOURCE-pre-swizzled k-groups (chunk = seg^(row&3)),
//    read with same XOR -> 8-way conflicts -> 4-way. LDS dest stays linear (rule 21).
// Output z_pre written bf16 (verified accuracy-neutral at R5).
__global__ __launch_bounds__(256, 2) void k_gemm(const float* __restrict__ H,
                                                 const unsigned short* __restrict__ B,
                                                 unsigned short* __restrict__ ZP) {
    __shared__ unsigned short As[2][128 * 40];   // padded: row stride 40 shorts (80B)
    __shared__ unsigned short Bs[2][128 * 32];
    const int tid = threadIdx.x;
    const int wid = tid >> 6, lane = tid & 63;
    const int hw = (int)blockIdx.x;
    const int xcd = hw & 7, nblk = (hw >> 3) & 7, mloc = hw >> 6;
    const int bm0 = (xcd * 32 + mloc) * 128;
    const int bn0 = nblk * 128;
    const int wr = wid >> 1, wc = wid & 1;
    const int fr = lane & 15, kq = lane >> 4;

    // A staging ownership: 256 threads cover 128 rows x 32 k (2 thr/row, 16 f32 each)
    const int arow = tid >> 1, ahalf = tid & 1;
    const float* ha = H + (size_t)(bm0 + arow) * HIDDEN + ahalf * 16;

    f32x4 acc[4][4] = {};

    auto loadA = [&](float4* f, int k0) {
        const float4* p = (const float4*)(ha + k0);
        #pragma unroll
        for (int q = 0; q < 4; q++) f[q] = p[q];
    };
    auto writeA = [&](int buf, const float4* f) {
        union { unsigned short us[16]; uint4 v[2]; } o;
        #pragma unroll
        for (int q = 0; q < 4; q++) {
            o.us[q * 4 + 0] = f2bf(f[q].x); o.us[q * 4 + 1] = f2bf(f[q].y);
            o.us[q * 4 + 2] = f2bf(f[q].z); o.us[q * 4 + 3] = f2bf(f[q].w);
        }
        uint4* dst = (uint4*)&As[buf][arow * 40 + ahalf * 16];
        dst[0] = o.v[0];
        dst[1] = o.v[1];
    };
    auto stageB = [&](int buf, int k0) {
        #pragma unroll
        for (int is = 0; is < 2; ++is) {
            int c = is * 256 + tid;
            int row = c >> 2, seg = c & 3;
            int seg_g = seg ^ (row & 3);   // source pre-swizzle (read applies same XOR)
            const unsigned short* gb = B + (size_t)(bn0 + row) * HIDDEN + k0 + seg_g * 8;
            void* lb = (void*)((char*)&Bs[buf][0] + (size_t)(is * 256 + wid * 64) * 16);
            __builtin_amdgcn_global_load_lds((const __attribute__((address_space(1))) void*)gb,
                                             (__attribute__((address_space(3))) void*)lb, 16, 0, 0);
        }
    };
    auto compute = [&](int buf) {
        bf16x8 av[4], bv[4];
        #pragma unroll
        for (int i = 0; i < 4; i++)
            av[i] = *(const bf16x8*)&As[buf][(wr * 64 + i * 16 + fr) * 40 + kq * 8];
        #pragma unroll
        for (int j = 0; j < 4; j++)
            bv[j] = *(const bf16x8*)&Bs[buf][(wc * 64 + j * 16 + fr) * 32 + (kq ^ (fr & 3)) * 8];
        #pragma unroll
        for (int i = 0; i < 4; i++)
            #pragma unroll
            for (int j = 0; j < 4; j++)
                acc[i][j] = __builtin_amdgcn_mfma_f32_16x16x32_bf16(av[i], bv[j], acc[i][j], 0, 0, 0);
    };

    float4 af[4];
    loadA(af, 0);
    stageB(0, 0);
    writeA(0, af);
    __syncthreads();
    int cur = 0;
    for (int t = 1; t < 32; t++) {
        float4 an[4];
        loadA(an, t * 32);        // issue f32 loads early (hide HBM under compute)
        stageB(cur ^ 1, t * 32);  // async B global->LDS
        compute(cur);
        writeA(cur ^ 1, an);      // cvt + padded ds_write after compute
        __syncthreads();
        cur ^= 1;
    }
    compute(cur);

    #pragma unroll
    for (int i = 0; i < 4; i++) {
        #pragma unroll
        for (int j = 0; j < 4; j++) {
            int col = bn0 + wc * 64 + j * 16 + fr;
            int rowb = bm0 + wr * 64 + i * 16 + kq * 4;
            #pragma unroll
            for (int r = 0; r < 4; r++)
                ZP[(size_t)(rowb + r) * HIDDEN + col] = f2bf(acc[i][j][r]);
        }
    }
}

// ---------------- LN + l2norm + prototype logits (bf16 z_pre in, f32 z out) ----------------
// One WAVE per row, no barriers in the row loop (verified structure, R2/R5).
__global__ __launch_bounds__(256) void k_ln(const unsigned short* __restrict__ zp,
                                            float* __restrict__ z, float* __restrict__ logits,
                                            const float* __restrict__ gamma, const float* __restrict__ beta,
                                            const float* __restrict__ pn, int waves_total) {
    __shared__ float sp[NPROTO * HIDDEN];
    const int tid = threadIdx.x, wid = tid >> 6, lane = tid & 63;
    #pragma unroll
    for (int i = 0; i < NPROTO * HIDDEN / 4 / 256; i++) {
        int idx = (i * 256 + tid) * 4;
        *(float4*)&sp[idx] = *(const float4*)&pn[idx];
    }
    __syncthreads();

    float4 g4[4], b4[4];
    #pragma unroll
    for (int c = 0; c < 4; c++) {
        g4[c] = *(const float4*)(gamma + lane * 4 + 256 * c);
        b4[c] = *(const float4*)(beta  + lane * 4 + 256 * c);
    }

    const float inv_n = 1.0f / 1024.0f;
    int gw = blockIdx.x * 4 + wid;
    for (int row = gw; row < MROWS; row += waves_total) {
        const unsigned short* zr = zp + (size_t)row * HIDDEN;
        float4 v[4];
        #pragma unroll
        for (int c = 0; c < 4; c++) {
            ushort4 u = *(const ushort4*)(zr + lane * 4 + 256 * c);
            v[c].x = bf2f(u.x); v[c].y = bf2f(u.y); v[c].z = bf2f(u.z); v[c].w = bf2f(u.w);
        }

        float s = 0.f, sq = 0.f;
        #pragma unroll
        for (int c = 0; c < 4; c++) {
            s  += v[c].x + v[c].y + v[c].z + v[c].w;
            sq += v[c].x * v[c].x + v[c].y * v[c].y + v[c].z * v[c].z + v[c].w * v[c].w;
        }
        #pragma unroll
        for (int m = 1; m < 64; m <<= 1) { s += __shfl_xor(s, m); sq += __shfl_xor(sq, m); }

        float mu  = s * inv_n;
        float var = sq * inv_n - mu * mu;
        float rs  = rsqrtf(var + 1e-5f);

        float* zo = z + (size_t)row * HIDDEN;
        #pragma unroll
        for (int c = 0; c < 4; c++) {
            v[c].x = (v[c].x - mu) * rs * g4[c].x + b4[c].x;
            v[c].y = (v[c].y - mu) * rs * g4[c].y + b4[c].y;
            v[c].z = (v[c].z - mu) * rs * g4[c].z + b4[c].z;
            v[c].w = (v[c].w - mu) * rs * g4[c].w + b4[c].w;
            *(float4*)(zo + lane * 4 + 256 * c) = v[c];
        }

        float part[10];
        #pragma unroll
        for (int k = 0; k < 10; k++) part[k] = 0.f;
        #pragma unroll
        for (int c = 0; c < 4; c++) {
            part[9] += v[c].x * v[c].x + v[c].y * v[c].y + v[c].z * v[c].z + v[c].w * v[c].w;
            #pragma unroll
            for (int k = 0; k < 9; k++) {
                float4 p = *(const float4*)&sp[k * HIDDEN + lane * 4 + 256 * c];
                part[k] += v[c].x * p.x + v[c].y * p.y + v[c].z * p.z + v[c].w * p.w;
            }
        }
        #pragma unroll
        for (int m = 1; m < 64; m <<= 1) {
            #pragma unroll
            for (int k = 0; k < 10; k++) part[k] += __shfl_xor(part[k], m);
        }
        if (lane == 0) {
            float inv = 1.0f / (fmaxf(sqrtf(part[9]), 1e-12f) * 0.07f);
            #pragma unroll
            for (int k = 0; k < 9; k++) logits[(size_t)row * NPROTO + k] = part[k] * inv;
        }
    }
}

extern "C" void kernel_launch(void* const* d_in, const int* in_sizes, int n_in,
                              void* d_out, int out_size, void* d_ws, size_t ws_size,
                              hipStream_t stream) {
    const float* h     = (const float*)d_in[0];
    const float* w     = (const float*)d_in[1];
    const float* mask  = (const float*)d_in[2];
    const float* gamma = (const float*)d_in[3];
    const float* beta  = (const float*)d_in[4];
    const float* proto = (const float*)d_in[5];
    float* out    = (float*)d_out;
    float* logits = out;                       // 32768*9 floats
    float* z      = out + (size_t)ZOFF;        // 32768*1024 floats

    char* ws = (char*)d_ws;
    unsigned short* zp = (unsigned short*)ws;                        // 64 MB bf16 z_pre
    unsigned short* wm = (unsigned short*)(ws + 67108864);           // 2 MB bf16 W*mask
    float*          pn = (float*)(ws + 67108864 + 2097152);          // 36 KB normalized protos

    k_conv_w<<<512, 256, 0, stream>>>(w, mask, wm, HIDDEN * HIDDEN / 8);
    k_proto<<<NPROTO, 256, 0, stream>>>(proto, pn);
    k_gemm<<<2048, 256, 0, stream>>>(h, wm, zp);
    k_ln<<<2048, 256, 0, stream>>>(zp, z, logits, gamma, beta, pn, 2048 * 4);
}

// Round 8
// 193.060 us; speedup vs baseline: 1.0391x; 1.0391x over previous
//
#include <hip/hip_runtime.h>
#include <stdint.h>

#define HIDDEN 1024
#define MROWS  32768
#define NPROTO 9
#define ZOFF   (MROWS * NPROTO)   // 294912 floats of logits, then z

typedef __bf16 bf16x8 __attribute__((ext_vector_type(8)));
typedef float  f32x4  __attribute__((ext_vector_type(4)));

__device__ __forceinline__ unsigned short f2bf(float f) {
    unsigned u = __float_as_uint(f);
    u += 0x7fffu + ((u >> 16) & 1u);   // round-to-nearest-even
    return (unsigned short)(u >> 16);
}
__device__ __forceinline__ float bf2f(unsigned short u) {
    return __uint_as_float(((unsigned)u) << 16);
}

// ---------------- prep: W*mask -> bf16 ----------------
__global__ void k_conv_w(const float* __restrict__ w, const float* __restrict__ m,
                         unsigned short* __restrict__ dst, int n8) {
    int i0 = blockIdx.x * blockDim.x + threadIdx.x;
    int stride = gridDim.x * blockDim.x;
    for (int i = i0; i < n8; i += stride) {
        const float4* pw = (const float4*)(w + (size_t)i * 8);
        const float4* pm = (const float4*)(m + (size_t)i * 8);
        float4 a = pw[0], b = pw[1], c = pm[0], d = pm[1];
        union { unsigned short us[8]; uint4 v; } o;
        o.us[0] = f2bf(a.x * c.x); o.us[1] = f2bf(a.y * c.y);
        o.us[2] = f2bf(a.z * c.z); o.us[3] = f2bf(a.w * c.w);
        o.us[4] = f2bf(b.x * d.x); o.us[5] = f2bf(b.y * d.y);
        o.us[6] = f2bf(b.z * d.z); o.us[7] = f2bf(b.w * d.w);
        *(uint4*)(dst + (size_t)i * 8) = o.v;
    }
}

// ---------------- prep: l2-normalized prototypes (first 9 rows) ----------------
__global__ void k_proto(const float* __restrict__ proto, float* __restrict__ pn) {
    __shared__ float red[4];
    int t = threadIdx.x, k = blockIdx.x;
    float4 v = *(const float4*)(proto + (size_t)k * HIDDEN + t * 4);
    float ss = v.x * v.x + v.y * v.y + v.z * v.z + v.w * v.w;
    #pragma unroll
    for (int m = 1; m < 64; m <<= 1) ss += __shfl_xor(ss, m);
    if ((t & 63) == 0) red[t >> 6] = ss;
    __syncthreads();
    ss = red[0] + red[1] + red[2] + red[3];
    float inv = 1.0f / fmaxf(sqrtf(ss), 1e-12f);
    float4 o; o.x = v.x * inv; o.y = v.y * inv; o.z = v.z * inv; o.w = v.w * inv;
    *(float4*)(pn + (size_t)k * HIDDEN + t * 4) = o;
}

// ---------------- main GEMM: zp[m][o] = bf16( sum_d h[m][d] * wm[o][d] ) ----------------
// 128x128/BK=32, 4 waves, XCD swizzle, global_load_lds staging for BOTH operands
// (R6-verified async path). A is staged as RAW F32 (16 KB/buf) and converted
// f32->bf16 at fragment-read time (v_cvt_pk). This deletes the separate conv_h
// pass AND frees the ws slot so z_pre can be bf16 (R7-verified accuracy-free).
// A chunk swizzle (rule 21: linear LDS dest, src chunk ^= row&7, same XOR on
// read): without it a fixed k-chunk is a 16-way conflict (128B rows, G4).
__global__ __launch_bounds__(256, 2) void k_gemm(const float* __restrict__ H,
                                                 const unsigned short* __restrict__ B,
                                                 unsigned short* __restrict__ ZP) {
    __shared__ char smem[49152];   // [0,32K) A f32 dbuf (16K each), [32K,48K) B bf16 dbuf
    const int tid = threadIdx.x;
    const int wid = tid >> 6, lane = tid & 63;
    const int hw = (int)blockIdx.x;
    const int xcd = hw & 7, nblk = (hw >> 3) & 7, mloc = hw >> 6;
    const int bm0 = (xcd * 32 + mloc) * 128;
    const int bn0 = nblk * 128;
    const int wr = wid >> 1, wc = wid & 1;
    const int fr = lane & 15, kq = lane >> 4;

    f32x4 acc[4][4] = {};

    // A tile: 128 rows x 32 f32 = 16 KB = 1024 chunks of 16B; 4 rounds x 256 thr.
    auto stageA = [&](int buf, int k0) {
        #pragma unroll
        for (int it = 0; it < 4; ++it) {
            int c = it * 256 + tid;
            int row = c >> 3, ch = c & 7;
            int g = ch ^ (row & 7);          // source chunk swizzle (involution)
            const float* ga = H + (size_t)(bm0 + row) * HIDDEN + k0 + g * 4;
            void* la = (void*)(smem + buf * 16384 + (size_t)(it * 256 + wid * 64) * 16);
            __builtin_amdgcn_global_load_lds((const __attribute__((address_space(1))) void*)ga,
                                             (__attribute__((address_space(3))) void*)la, 16, 0, 0);
        }
    };
    // B tile: 128 rows x 32 bf16 = 8 KB = 512 chunks; 2 rounds x 256 thr (R6 exact).
    auto stageB = [&](int buf, int k0) {
        #pragma unroll
        for (int is = 0; is < 2; ++is) {
            int c = is * 256 + tid;
            int row = c >> 2, seg = c & 3;
            const unsigned short* gb = B + (size_t)(bn0 + row) * HIDDEN + k0 + seg * 8;
            void* lb = (void*)(smem + 32768 + buf * 8192 + (size_t)(is * 256 + wid * 64) * 16);
            __builtin_amdgcn_global_load_lds((const __attribute__((address_space(1))) void*)gb,
                                             (__attribute__((address_space(3))) void*)lb, 16, 0, 0);
        }
    };

    auto compute = [&](int buf) {
        const char* as = smem + buf * 16384;
        const unsigned short* bs = (const unsigned short*)(smem + 32768 + buf * 8192);
        bf16x8 av[4], bv[4];
        #pragma unroll
        for (int i = 0; i < 4; i++) {
            int r = wr * 64 + i * 16 + fr;
            f32x4 lo = *(const f32x4*)(as + r * 128 + (((2 * kq)     ^ (fr & 7)) * 16));
            f32x4 hi = *(const f32x4*)(as + r * 128 + (((2 * kq + 1) ^ (fr & 7)) * 16));
            bf16x8 a;
            a[0] = (__bf16)lo[0]; a[1] = (__bf16)lo[1]; a[2] = (__bf16)lo[2]; a[3] = (__bf16)lo[3];
            a[4] = (__bf16)hi[0]; a[5] = (__bf16)hi[1]; a[6] = (__bf16)hi[2]; a[7] = (__bf16)hi[3];
            av[i] = a;
        }
        #pragma unroll
        for (int j = 0; j < 4; j++)
            bv[j] = *(const bf16x8*)&bs[(wc * 64 + j * 16 + fr) * 32 + kq * 8];
        #pragma unroll
        for (int i = 0; i < 4; i++)
            #pragma unroll
            for (int j = 0; j < 4; j++)
                acc[i][j] = __builtin_amdgcn_mfma_f32_16x16x32_bf16(av[i], bv[j], acc[i][j], 0, 0, 0);
    };

    stageA(0, 0);
    stageB(0, 0);
    __syncthreads();
    int cur = 0;
    for (int t = 1; t < 32; t++) {
        stageA(cur ^ 1, t * 32);
        stageB(cur ^ 1, t * 32);
        compute(cur);
        __syncthreads();
        cur ^= 1;
    }
    compute(cur);

    #pragma unroll
    for (int i = 0; i < 4; i++) {
        #pragma unroll
        for (int j = 0; j < 4; j++) {
            int col = bn0 + wc * 64 + j * 16 + fr;
            int rowb = bm0 + wr * 64 + i * 16 + kq * 4;
            #pragma unroll
            for (int r = 0; r < 4; r++)
                ZP[(size_t)(rowb + r) * HIDDEN + col] = f2bf(acc[i][j][r]);
        }
    }
}

// ---------------- LN + l2norm + prototype logits (bf16 z_pre in, f32 z out) ----------------
// One WAVE per row, no barriers in the row loop (verified R2/R5/R7).
__global__ __launch_bounds__(256) void k_ln(const unsigned short* __restrict__ zp,
                                            float* __restrict__ z, float* __restrict__ logits,
                                            const float* __restrict__ gamma, const float* __restrict__ beta,
                                            const float* __restrict__ pn, int waves_total) {
    __shared__ float sp[NPROTO * HIDDEN];
    const int tid = threadIdx.x, wid = tid >> 6, lane = tid & 63;
    #pragma unroll
    for (int i = 0; i < NPROTO * HIDDEN / 4 / 256; i++) {
        int idx = (i * 256 + tid) * 4;
        *(float4*)&sp[idx] = *(const float4*)&pn[idx];
    }
    __syncthreads();

    float4 g4[4], b4[4];
    #pragma unroll
    for (int c = 0; c < 4; c++) {
        g4[c] = *(const float4*)(gamma + lane * 4 + 256 * c);
        b4[c] = *(const float4*)(beta  + lane * 4 + 256 * c);
    }

    const float inv_n = 1.0f / 1024.0f;
    int gw = blockIdx.x * 4 + wid;
    for (int row = gw; row < MROWS; row += waves_total) {
        const unsigned short* zr = zp + (size_t)row * HIDDEN;
        float4 v[4];
        #pragma unroll
        for (int c = 0; c < 4; c++) {
            ushort4 u = *(const ushort4*)(zr + lane * 4 + 256 * c);
            v[c].x = bf2f(u.x); v[c].y = bf2f(u.y); v[c].z = bf2f(u.z); v[c].w = bf2f(u.w);
        }

        float s = 0.f, sq = 0.f;
        #pragma unroll
        for (int c = 0; c < 4; c++) {
            s  += v[c].x + v[c].y + v[c].z + v[c].w;
            sq += v[c].x * v[c].x + v[c].y * v[c].y + v[c].z * v[c].z + v[c].w * v[c].w;
        }
        #pragma unroll
        for (int m = 1; m < 64; m <<= 1) { s += __shfl_xor(s, m); sq += __shfl_xor(sq, m); }

        float mu  = s * inv_n;
        float var = sq * inv_n - mu * mu;
        float rs  = rsqrtf(var + 1e-5f);

        float* zo = z + (size_t)row * HIDDEN;
        #pragma unroll
        for (int c = 0; c < 4; c++) {
            v[c].x = (v[c].x - mu) * rs * g4[c].x + b4[c].x;
            v[c].y = (v[c].y - mu) * rs * g4[c].y + b4[c].y;
            v[c].z = (v[c].z - mu) * rs * g4[c].z + b4[c].z;
            v[c].w = (v[c].w - mu) * rs * g4[c].w + b4[c].w;
            *(float4*)(zo + lane * 4 + 256 * c) = v[c];
        }

        float part[10];
        #pragma unroll
        for (int k = 0; k < 10; k++) part[k] = 0.f;
        #pragma unroll
        for (int c = 0; c < 4; c++) {
            part[9] += v[c].x * v[c].x + v[c].y * v[c].y + v[c].z * v[c].z + v[c].w * v[c].w;
            #pragma unroll
            for (int k = 0; k < 9; k++) {
                float4 p = *(const float4*)&sp[k * HIDDEN + lane * 4 + 256 * c];
                part[k] += v[c].x * p.x + v[c].y * p.y + v[c].z * p.z + v[c].w * p.w;
            }
        }
        #pragma unroll
        for (int m = 1; m < 64; m <<= 1) {
            #pragma unroll
            for (int k = 0; k < 10; k++) part[k] += __shfl_xor(part[k], m);
        }
        if (lane == 0) {
            float inv = 1.0f / (fmaxf(sqrtf(part[9]), 1e-12f) * 0.07f);
            #pragma unroll
            for (int k = 0; k < 9; k++) logits[(size_t)row * NPROTO + k] = part[k] * inv;
        }
    }
}

extern "C" void kernel_launch(void* const* d_in, const int* in_sizes, int n_in,
                              void* d_out, int out_size, void* d_ws, size_t ws_size,
                              hipStream_t stream) {
    const float* h     = (const float*)d_in[0];
    const float* w     = (const float*)d_in[1];
    const float* mask  = (const float*)d_in[2];
    const float* gamma = (const float*)d_in[3];
    const float* beta  = (const float*)d_in[4];
    const float* proto = (const float*)d_in[5];
    float* out    = (float*)d_out;
    float* logits = out;                       // 32768*9 floats
    float* z      = out + (size_t)ZOFF;        // 32768*1024 floats

    char* ws = (char*)d_ws;
    unsigned short* zp = (unsigned short*)ws;                        // 64 MB bf16 z_pre
    unsigned short* wm = (unsigned short*)(ws + 67108864);           // 2 MB bf16 W*mask
    float*          pn = (float*)(ws + 67108864 + 2097152);          // 36 KB normalized protos

    k_conv_w<<<512, 256, 0, stream>>>(w, mask, wm, HIDDEN * HIDDEN / 8);
    k_proto<<<NPROTO, 256, 0, stream>>>(proto, pn);
    k_gemm<<<2048, 256, 0, stream>>>(h, wm, zp);
    k_ln<<<2048, 256, 0, stream>>>(zp, z, logits, gamma, beta, pn, 2048 * 4);
}

// Round 9
// 171.190 us; speedup vs baseline: 1.1719x; 1.1278x over previous
//
#include <hip/hip_runtime.h>
#include <stdint.h>

#define HIDDEN 1024
#define MROWS  32768
#define NPROTO 9
#define ZOFF   (MROWS * NPROTO)   // 294912 floats of logits, then z

typedef __bf16 bf16x8 __attribute__((ext_vector_type(8)));
typedef float  f32x4  __attribute__((ext_vector_type(4)));

__device__ __forceinline__ unsigned short f2bf(float f) {
    unsigned u = __float_as_uint(f);
    u += 0x7fffu + ((u >> 16) & 1u);   // round-to-nearest-even
    return (unsigned short)(u >> 16);
}
__device__ __forceinline__ float bf2f(unsigned short u) {
    return __uint_as_float(((unsigned)u) << 16);
}

// ---------------- prep: h (f32) -> bf16 ----------------
__global__ void k_conv_h(const float* __restrict__ src, unsigned short* __restrict__ dst, int n8) {
    int i0 = blockIdx.x * blockDim.x + threadIdx.x;
    int stride = gridDim.x * blockDim.x;
    for (int i = i0; i < n8; i += stride) {
        const float4* p = (const float4*)(src + (size_t)i * 8);
        float4 a = p[0], b = p[1];
        union { unsigned short us[8]; uint4 v; } o;
        o.us[0] = f2bf(a.x); o.us[1] = f2bf(a.y); o.us[2] = f2bf(a.z); o.us[3] = f2bf(a.w);
        o.us[4] = f2bf(b.x); o.us[5] = f2bf(b.y); o.us[6] = f2bf(b.z); o.us[7] = f2bf(b.w);
        *(uint4*)(dst + (size_t)i * 8) = o.v;
    }
}

// ---------------- prep: W*mask -> bf16 ----------------
__global__ void k_conv_w(const float* __restrict__ w, const float* __restrict__ m,
                         unsigned short* __restrict__ dst, int n8) {
    int i0 = blockIdx.x * blockDim.x + threadIdx.x;
    int stride = gridDim.x * blockDim.x;
    for (int i = i0; i < n8; i += stride) {
        const float4* pw = (const float4*)(w + (size_t)i * 8);
        const float4* pm = (const float4*)(m + (size_t)i * 8);
        float4 a = pw[0], b = pw[1], c = pm[0], d = pm[1];
        union { unsigned short us[8]; uint4 v; } o;
        o.us[0] = f2bf(a.x * c.x); o.us[1] = f2bf(a.y * c.y);
        o.us[2] = f2bf(a.z * c.z); o.us[3] = f2bf(a.w * c.w);
        o.us[4] = f2bf(b.x * d.x); o.us[5] = f2bf(b.y * d.y);
        o.us[6] = f2bf(b.z * d.z); o.us[7] = f2bf(b.w * d.w);
        *(uint4*)(dst + (size_t)i * 8) = o.v;
    }
}

// ---------------- prep: l2-normalized prototypes (first 9 rows) ----------------
__global__ void k_proto(const float* __restrict__ proto, float* __restrict__ pn) {
    __shared__ float red[4];
    int t = threadIdx.x, k = blockIdx.x;
    float4 v = *(const float4*)(proto + (size_t)k * HIDDEN + t * 4);
    float ss = v.x * v.x + v.y * v.y + v.z * v.z + v.w * v.w;
    #pragma unroll
    for (int m = 1; m < 64; m <<= 1) ss += __shfl_xor(ss, m);
    if ((t & 63) == 0) red[t >> 6] = ss;
    __syncthreads();
    ss = red[0] + red[1] + red[2] + red[3];
    float inv = 1.0f / fmaxf(sqrtf(ss), 1e-12f);
    float4 o; o.x = v.x * inv; o.y = v.y * inv; o.z = v.z * inv; o.w = v.w * inv;
    *(float4*)(pn + (size_t)k * HIDDEN + t * 4) = o;
}

// ---------------- main GEMM (R6-verified K-loop; templated epilogue dtype) ----------------
// 128x128/BK=32, 4 waves, global_load_lds for A and B, 2-phase dbuf, XCD swizzle.
template<int BF16OUT>
__global__ __launch_bounds__(256, 2) void k_gemm(const unsigned short* __restrict__ A,
                                                 const unsigned short* __restrict__ B,
                                                 void* __restrict__ Cv) {
    __shared__ unsigned short As[2][128 * 32];
    __shared__ unsigned short Bs[2][128 * 32];
    const int tid = threadIdx.x;
    const int wid = tid >> 6, lane = tid & 63;
    const int hw = (int)blockIdx.x;
    const int xcd = hw & 7, nblk = (hw >> 3) & 7, mloc = hw >> 6;
    const int bm0 = (xcd * 32 + mloc) * 128;
    const int bn0 = nblk * 128;
    const int wr = wid >> 1, wc = wid & 1;
    const int fr = lane & 15, kq = lane >> 4;

    f32x4 acc[4][4] = {};

    auto stage = [&](int buf, int k0) {
        #pragma unroll
        for (int is = 0; is < 2; ++is) {
            int c = is * 256 + tid;
            int row = c >> 2, seg = c & 3;
            const unsigned short* ga = A + (size_t)(bm0 + row) * HIDDEN + k0 + seg * 8;
            void* la = (void*)((char*)&As[buf][0] + (size_t)(is * 256 + wid * 64) * 16);
            __builtin_amdgcn_global_load_lds((const __attribute__((address_space(1))) void*)ga,
                                             (__attribute__((address_space(3))) void*)la, 16, 0, 0);
            const unsigned short* gb = B + (size_t)(bn0 + row) * HIDDEN + k0 + seg * 8;
            void* lb = (void*)((char*)&Bs[buf][0] + (size_t)(is * 256 + wid * 64) * 16);
            __builtin_amdgcn_global_load_lds((const __attribute__((address_space(1))) void*)gb,
                                             (__attribute__((address_space(3))) void*)lb, 16, 0, 0);
        }
    };

    auto compute = [&](int buf) {
        bf16x8 av[4], bv[4];
        #pragma unroll
        for (int i = 0; i < 4; i++)
            av[i] = *(const bf16x8*)&As[buf][(wr * 64 + i * 16 + fr) * 32 + kq * 8];
        #pragma unroll
        for (int j = 0; j < 4; j++)
            bv[j] = *(const bf16x8*)&Bs[buf][(wc * 64 + j * 16 + fr) * 32 + kq * 8];
        #pragma unroll
        for (int i = 0; i < 4; i++)
            #pragma unroll
            for (int j = 0; j < 4; j++)
                acc[i][j] = __builtin_amdgcn_mfma_f32_16x16x32_bf16(av[i], bv[j], acc[i][j], 0, 0, 0);
    };

    stage(0, 0);
    __syncthreads();
    int cur = 0;
    for (int t = 1; t < 32; t++) {
        stage(cur ^ 1, t * 32);
        compute(cur);
        __syncthreads();
        cur ^= 1;
    }
    compute(cur);

    #pragma unroll
    for (int i = 0; i < 4; i++) {
        #pragma unroll
        for (int j = 0; j < 4; j++) {
            int col = bn0 + wc * 64 + j * 16 + fr;
            int rowb = bm0 + wr * 64 + i * 16 + kq * 4;
            #pragma unroll
            for (int r = 0; r < 4; r++) {
                if constexpr (BF16OUT)
                    ((unsigned short*)Cv)[(size_t)(rowb + r) * HIDDEN + col] = f2bf(acc[i][j][r]);
                else
                    ((float*)Cv)[(size_t)(rowb + r) * HIDDEN + col] = acc[i][j][r];
            }
        }
    }
}

// ---------------- LN + l2norm + logits, bf16 z_pre input (R7/R8-verified, ~35 us) ----------------
__global__ __launch_bounds__(256) void k_ln_b(const unsigned short* __restrict__ zp,
                                              float* __restrict__ z, float* __restrict__ logits,
                                              const float* __restrict__ gamma, const float* __restrict__ beta,
                                              const float* __restrict__ pn, int waves_total) {
    __shared__ float sp[NPROTO * HIDDEN];
    const int tid = threadIdx.x, wid = tid >> 6, lane = tid & 63;
    #pragma unroll
    for (int i = 0; i < NPROTO * HIDDEN / 4 / 256; i++) {
        int idx = (i * 256 + tid) * 4;
        *(float4*)&sp[idx] = *(const float4*)&pn[idx];
    }
    __syncthreads();

    float4 g4[4], b4[4];
    #pragma unroll
    for (int c = 0; c < 4; c++) {
        g4[c] = *(const float4*)(gamma + lane * 4 + 256 * c);
        b4[c] = *(const float4*)(beta  + lane * 4 + 256 * c);
    }

    const float inv_n = 1.0f / 1024.0f;
    int gw = blockIdx.x * 4 + wid;
    for (int row = gw; row < MROWS; row += waves_total) {
        const unsigned short* zr = zp + (size_t)row * HIDDEN;
        float4 v[4];
        #pragma unroll
        for (int c = 0; c < 4; c++) {
            ushort4 u = *(const ushort4*)(zr + lane * 4 + 256 * c);
            v[c].x = bf2f(u.x); v[c].y = bf2f(u.y); v[c].z = bf2f(u.z); v[c].w = bf2f(u.w);
        }

        float s = 0.f, sq = 0.f;
        #pragma unroll
        for (int c = 0; c < 4; c++) {
            s  += v[c].x + v[c].y + v[c].z + v[c].w;
            sq += v[c].x * v[c].x + v[c].y * v[c].y + v[c].z * v[c].z + v[c].w * v[c].w;
        }
        #pragma unroll
        for (int m = 1; m < 64; m <<= 1) { s += __shfl_xor(s, m); sq += __shfl_xor(sq, m); }

        float mu  = s * inv_n;
        float var = sq * inv_n - mu * mu;
        float rs  = rsqrtf(var + 1e-5f);

        float* zo = z + (size_t)row * HIDDEN;
        #pragma unroll
        for (int c = 0; c < 4; c++) {
            v[c].x = (v[c].x - mu) * rs * g4[c].x + b4[c].x;
            v[c].y = (v[c].y - mu) * rs * g4[c].y + b4[c].y;
            v[c].z = (v[c].z - mu) * rs * g4[c].z + b4[c].z;
            v[c].w = (v[c].w - mu) * rs * g4[c].w + b4[c].w;
            *(float4*)(zo + lane * 4 + 256 * c) = v[c];
        }

        float part[10];
        #pragma unroll
        for (int k = 0; k < 10; k++) part[k] = 0.f;
        #pragma unroll
        for (int c = 0; c < 4; c++) {
            part[9] += v[c].x * v[c].x + v[c].y * v[c].y + v[c].z * v[c].z + v[c].w * v[c].w;
            #pragma unroll
            for (int k = 0; k < 9; k++) {
                float4 p = *(const float4*)&sp[k * HIDDEN + lane * 4 + 256 * c];
                part[k] += v[c].x * p.x + v[c].y * p.y + v[c].z * p.z + v[c].w * p.w;
            }
        }
        #pragma unroll
        for (int m = 1; m < 64; m <<= 1) {
            #pragma unroll
            for (int k = 0; k < 10; k++) part[k] += __shfl_xor(part[k], m);
        }
        if (lane == 0) {
            float inv = 1.0f / (fmaxf(sqrtf(part[9]), 1e-12f) * 0.07f);
            #pragma unroll
            for (int k = 0; k < 9; k++) logits[(size_t)row * NPROTO + k] = part[k] * inv;
        }
    }
}

// ---------------- LN + l2norm + logits, f32 in-place (R6-verified fallback) ----------------
__global__ __launch_bounds__(256) void k_ln_a(float* __restrict__ z, float* __restrict__ logits,
                                              const float* __restrict__ gamma, const float* __restrict__ beta,
                                              const float* __restrict__ pn, int waves_total) {
    __shared__ float sp[NPROTO * HIDDEN];
    const int tid = threadIdx.x, wid = tid >> 6, lane = tid & 63;
    #pragma unroll
    for (int i = 0; i < NPROTO * HIDDEN / 4 / 256; i++) {
        int idx = (i * 256 + tid) * 4;
        *(float4*)&sp[idx] = *(const float4*)&pn[idx];
    }
    __syncthreads();

    float4 g4[4], b4[4];
    #pragma unroll
    for (int c = 0; c < 4; c++) {
        g4[c] = *(const float4*)(gamma + lane * 4 + 256 * c);
        b4[c] = *(const float4*)(beta  + lane * 4 + 256 * c);
    }

    const float inv_n = 1.0f / 1024.0f;
    int gw = blockIdx.x * 4 + wid;
    for (int row = gw; row < MROWS; row += waves_total) {
        float* zr = z + (size_t)row * HIDDEN;
        float4 v[4];
        #pragma unroll
        for (int c = 0; c < 4; c++) v[c] = *(const float4*)(zr + lane * 4 + 256 * c);

        float s = 0.f, sq = 0.f;
        #pragma unroll
        for (int c = 0; c < 4; c++) {
            s  += v[c].x + v[c].y + v[c].z + v[c].w;
            sq += v[c].x * v[c].x + v[c].y * v[c].y + v[c].z * v[c].z + v[c].w * v[c].w;
        }
        #pragma unroll
        for (int m = 1; m < 64; m <<= 1) { s += __shfl_xor(s, m); sq += __shfl_xor(sq, m); }

        float mu  = s * inv_n;
        float var = sq * inv_n - mu * mu;
        float rs  = rsqrtf(var + 1e-5f);

        #pragma unroll
        for (int c = 0; c < 4; c++) {
            v[c].x = (v[c].x - mu) * rs * g4[c].x + b4[c].x;
            v[c].y = (v[c].y - mu) * rs * g4[c].y + b4[c].y;
            v[c].z = (v[c].z - mu) * rs * g4[c].z + b4[c].z;
            v[c].w = (v[c].w - mu) * rs * g4[c].w + b4[c].w;
            *(float4*)(zr + lane * 4 + 256 * c) = v[c];
        }

        float part[10];
        #pragma unroll
        for (int k = 0; k < 10; k++) part[k] = 0.f;
        #pragma unroll
        for (int c = 0; c < 4; c++) {
            part[9] += v[c].x * v[c].x + v[c].y * v[c].y + v[c].z * v[c].z + v[c].w * v[c].w;
            #pragma unroll
            for (int k = 0; k < 9; k++) {
                float4 p = *(const float4*)&sp[k * HIDDEN + lane * 4 + 256 * c];
                part[k] += v[c].x * p.x + v[c].y * p.y + v[c].z * p.z + v[c].w * p.w;
            }
        }
        #pragma unroll
        for (int m = 1; m < 64; m <<= 1) {
            #pragma unroll
            for (int k = 0; k < 10; k++) part[k] += __shfl_xor(part[k], m);
        }
        if (lane == 0) {
            float inv = 1.0f / (fmaxf(sqrtf(part[9]), 1e-12f) * 0.07f);
            #pragma unroll
            for (int k = 0; k < 9; k++) logits[(size_t)row * NPROTO + k] = part[k] * inv;
        }
    }
}

extern "C" void kernel_launch(void* const* d_in, const int* in_sizes, int n_in,
                              void* d_out, int out_size, void* d_ws, size_t ws_size,
                              hipStream_t stream) {
    const float* h     = (const float*)d_in[0];
    const float* w     = (const float*)d_in[1];
    const float* mask  = (const float*)d_in[2];
    const float* gamma = (const float*)d_in[3];
    const float* beta  = (const float*)d_in[4];
    const float* proto = (const float*)d_in[5];
    float* out    = (float*)d_out;
    float* logits = out;                       // 32768*9 floats
    float* z      = out + (size_t)ZOFF;        // 32768*1024 floats

    char* ws = (char*)d_ws;
    unsigned short* hb = (unsigned short*)ws;                        // 64 MB bf16 h
    unsigned short* wm = (unsigned short*)(ws + 67108864);           // 2 MB bf16 W*mask
    float*          pn = (float*)(ws + 67108864 + 2097152);          // 36 KB normalized protos
    unsigned short* zp = (unsigned short*)(ws + 67108864 + 2097152 + 65536); // 64 MB bf16 z_pre (if fits)

    const size_t need_bf16 = 67108864ull + 2097152ull + 65536ull + 67108864ull;

    k_conv_h<<<4096, 256, 0, stream>>>(h, hb, MROWS * HIDDEN / 8);
    k_conv_w<<<512, 256, 0, stream>>>(w, mask, wm, HIDDEN * HIDDEN / 8);
    k_proto<<<NPROTO, 256, 0, stream>>>(proto, pn);
    if (ws_size >= need_bf16) {
        k_gemm<1><<<2048, 256, 0, stream>>>(hb, wm, zp);
        k_ln_b<<<2048, 256, 0, stream>>>(zp, z, logits, gamma, beta, pn, 2048 * 4);
    } else {
        k_gemm<0><<<2048, 256, 0, stream>>>(hb, wm, z);
        k_ln_a<<<2048, 256, 0, stream>>>(z, logits, gamma, beta, pn, 2048 * 4);
    }
}